// Round 10
// baseline (295.101 us; speedup 1.0000x reference)
//
#include <hip/hip_runtime.h>
#include <stdint.h>

// R10: candidate (deep-pipelined staged MFMA kernel -> d_out) + a sacrificial
// cold-read bandwidth probe over all of d_ws (-> top-5 counters). The probe
// answers: can a global_load_lds fire-hose stream cold HBM at ~6 TB/s in this
// harness context, or is the cold ceiling ~2.2 TB/s (as all R6-R9 structures
// suggest)? Candidate tests the "per-wave prefetch window too shallow /
// compiler-defeated vmcnt" theory with a 2-panel-deep compile-time pipeline.
//
// Math (verified R4-R9): M = sum_t x[t] (x) x[t+1], K=2047 padded to 2048 by
// row-clamp (bogus symmetric term cancels); A = 0.5*(M - M^T - x0(x)L1 +
// L1(x)x0); fp32 -> truncation hi/lo split, 12 MFMA/panel, absmax ~0.5.

constexpr int kB   = 512;
constexpr int kL   = 2048;
constexpr int kD   = 32;
constexpr int kOut = 528;
constexpr int kPan = 32;            // rows per K=32 panel
constexpr int kTw  = 256;           // rows per wave
constexpr int kNP  = kTw / kPan;    // 8 panels
constexpr int kCh  = 264;           // dwords per 8-row chunk (256 + 8 skew)
constexpr int kPB  = 5 * kCh;       // panel buffer: 4 chunks + halo chunk

typedef __attribute__((ext_vector_type(8))) short bfrag;
typedef __attribute__((ext_vector_type(4))) float f4acc;
union FragU { uint32_t u[4]; bfrag f; };

#if defined(__has_builtin)
#if __has_builtin(__builtin_amdgcn_global_load_lds)
#define LOGSIG_ASYNC_LDS 1
#endif
#endif

__device__ __forceinline__ void async_ld16(const uint32_t* g, uint32_t* l, int lane) {
#ifdef LOGSIG_ASYNC_LDS
    auto* gp = reinterpret_cast<const __attribute__((address_space(1))) uint32_t*>(
        reinterpret_cast<uintptr_t>(g));
    auto* lp = reinterpret_cast<__attribute__((address_space(3))) uint32_t*>(
        reinterpret_cast<uintptr_t>(l));
    __builtin_amdgcn_global_load_lds(gp, lp, 16, 0, 0);
#else
    *(float4*)(l + lane * 4) = *(const float4*)g;
#endif
}

// ------------------------------------------------------------- candidate ---
__global__ __launch_bounds__(256, 2)
void logsig_mfma(const float* __restrict__ x, float* __restrict__ out) {
    __shared__ __align__(16) uint32_t sStage[4][3][kPB];   // 63.4 KB, wave-private
    __shared__ float sx0[kD], sL1[kD];

    const int b     = blockIdx.x >> 1;
    const int chunk = blockIdx.x & 1;
    const int tid   = threadIdx.x;
    const int wave  = tid >> 6;
    const int lane  = tid & 63;
    const int m     = lane & 15;
    const int q     = lane >> 4;

    const float* __restrict__ xb = x + (size_t)b * (kL * kD);
    const int t0w = chunk * 1024 + wave * kTw;

    // stage one 40-row panel (32 rows + 8-row halo chunk), 5 x 1KB line-dense
    auto stage_panel = [&](int p, int buf) {
        uint32_t* dst = &sStage[wave][buf][0];
        const int rbase = t0w + p * kPan;
        #pragma unroll
        for (int c = 0; c < 5; ++c) {
            int r = rbase + c * 8 + (lane >> 3);
            r = r < kL - 1 ? r : kL - 1;                    // clamp (halo/tail)
            const uint32_t* g = (const uint32_t*)xb + (size_t)r * kD + (lane & 7) * 4;
            async_ld16(g, dst + c * kCh, lane);
        }
    };

    f4acc acc[4];
    #pragma unroll
    for (int t = 0; t < 4; ++t)
        #pragma unroll
        for (int e = 0; e < 4; ++e) acc[t][e] = 0.0f;

    auto make_frags = [&](const uint32_t* e, FragU& AH, FragU& AL,
                          FragU& BH, FragU& BL) {
        uint32_t l[9];
        #pragma unroll
        for (int j = 0; j < 9; ++j) {
            const uint32_t fh = e[j] & 0xffff0000u;
            const float r = __builtin_bit_cast(float, e[j])
                          - __builtin_bit_cast(float, fh);
            l[j] = __builtin_bit_cast(uint32_t, r);
        }
        #pragma unroll
        for (int d = 0; d < 4; ++d) {
            AH.u[d] = __builtin_amdgcn_perm(e[2*d+1], e[2*d],   0x07060302u);
            AL.u[d] = __builtin_amdgcn_perm(l[2*d+1], l[2*d],   0x07060302u);
            BH.u[d] = __builtin_amdgcn_perm(e[2*d+2], e[2*d+1], 0x07060302u);
            BL.u[d] = __builtin_amdgcn_perm(l[2*d+2], l[2*d+1], 0x07060302u);
        }
    };

    stage_panel(0, 0);     //  5 outstanding
    stage_panel(1, 1);     // 10 outstanding

    #pragma unroll
    for (int p = 0; p < kNP; ++p) {
        if (p + 2 < kNP) {
            stage_panel(p + 2, (p + 2) % 3);                 // 15 outstanding
            asm volatile("s_waitcnt vmcnt(10)" ::: "memory"); // panel p ready
        } else if (p + 1 < kNP) {
            asm volatile("s_waitcnt vmcnt(5)" ::: "memory");
        } else {
            asm volatile("s_waitcnt vmcnt(0)" ::: "memory");
        }

        const uint32_t* sb = &sStage[wave][p % 3][0];
        uint32_t e0[9], e1[9];
        #pragma unroll
        for (int j = 0; j < 8; ++j) {
            const int a = q * kCh + j * 32 + m;   // bank (8q+m)%32: 2-way, free
            e0[j] = sb[a];
            e1[j] = sb[a + 16];
        }
        {
            const int a8 = (q + 1) * kCh + m;     // row 8q+8 = chunk q+1, row 0
            e0[8] = sb[a8];
            e1[8] = sb[a8 + 16];
        }

        FragU A0H, A0L, B0H, B0L, A1H, A1L, B1H, B1L;
        make_frags(e0, A0H, A0L, B0H, B0L);
        make_frags(e1, A1H, A1L, B1H, B1L);

        acc[0] = __builtin_amdgcn_mfma_f32_16x16x32_bf16(A0H.f, B0H.f, acc[0], 0, 0, 0);
        acc[0] = __builtin_amdgcn_mfma_f32_16x16x32_bf16(A0H.f, B0L.f, acc[0], 0, 0, 0);
        acc[0] = __builtin_amdgcn_mfma_f32_16x16x32_bf16(A0L.f, B0H.f, acc[0], 0, 0, 0);
        acc[1] = __builtin_amdgcn_mfma_f32_16x16x32_bf16(A0H.f, B1H.f, acc[1], 0, 0, 0);
        acc[1] = __builtin_amdgcn_mfma_f32_16x16x32_bf16(A0H.f, B1L.f, acc[1], 0, 0, 0);
        acc[1] = __builtin_amdgcn_mfma_f32_16x16x32_bf16(A0L.f, B1H.f, acc[1], 0, 0, 0);
        acc[2] = __builtin_amdgcn_mfma_f32_16x16x32_bf16(A1H.f, B0H.f, acc[2], 0, 0, 0);
        acc[2] = __builtin_amdgcn_mfma_f32_16x16x32_bf16(A1H.f, B0L.f, acc[2], 0, 0, 0);
        acc[2] = __builtin_amdgcn_mfma_f32_16x16x32_bf16(A1L.f, B0H.f, acc[2], 0, 0, 0);
        acc[3] = __builtin_amdgcn_mfma_f32_16x16x32_bf16(A1H.f, B1H.f, acc[3], 0, 0, 0);
        acc[3] = __builtin_amdgcn_mfma_f32_16x16x32_bf16(A1H.f, B1L.f, acc[3], 0, 0, 0);
        acc[3] = __builtin_amdgcn_mfma_f32_16x16x32_bf16(A1L.f, B1H.f, acc[3], 0, 0, 0);
    }

    // ---- epilogue: overlay per-wave M on dead stage buffers, reduce, emit ----
    float* sWw = (float*)&sStage[wave][0][0];
    #pragma unroll
    for (int t = 0; t < 4; ++t) {
        const int tr = t >> 1, tc = t & 1;
        #pragma unroll
        for (int e = 0; e < 4; ++e) {
            const int row = 16 * tr + q * 4 + e;   // C/D layout (m89-verified)
            const int col = 16 * tc + m;
            sWw[row * kD + col] = acc[t][e];
        }
    }
    if (tid < kD) {
        const float x0v = xb[tid];
        const float xev = xb[(size_t)(kL - 1) * kD + tid];
        sx0[tid] = x0v;
        sL1[tid] = xev - x0v;
    }
    __syncthreads();

    float* sW0 = (float*)&sStage[0][0][0];
    for (int c = tid; c < kD * kD; c += 256)
        sW0[c] += ((float*)&sStage[1][0][0])[c]
                + ((float*)&sStage[2][0][0])[c]
                + ((float*)&sStage[3][0][0])[c];
    __syncthreads();

    float* ob = out + (size_t)b * kOut;
    for (int o = tid; o < kOut; o += 256) {
        if (o < 32) {
            if (chunk == 0) ob[o] = sL1[o];
        } else {
            int p = o - 32, i = 0;
            while (p >= 31 - i) { p -= 31 - i; ++i; }
            const int j = i + 1 + p;
            float v = 0.5f * (sW0[i * kD + j] - sW0[j * kD + i]);
            if (chunk == 0)
                v += 0.5f * (sx0[j] * sL1[i] - sx0[i] * sL1[j]);
            atomicAdd(ob + o, v);
        }
    }
}

// ------------------------------------------------------------ BW probe -----
// Streams all of d_ws (cold: the 0xAA fill just flushed L3) via back-to-back
// global_load_lds dwordx4, one vmcnt(0) at the end. Duration >= 80us even at
// full BW -> lands in top-5; its hbm_gbps IS the cold staged-read ceiling.
__global__ __launch_bounds__(256, 8)
void bw_probe(const uint32_t* __restrict__ ws, uint32_t* __restrict__ sink,
              int dwPerBlock) {
    __shared__ __align__(16) uint32_t pb[4][1024];
    const int tid  = threadIdx.x;
    const int wave = tid >> 6;
    const int lane = tid & 63;
    const int dwPerWave = dwPerBlock >> 2;
    const uint32_t* base = ws + (size_t)blockIdx.x * dwPerBlock
                              + (size_t)wave * dwPerWave;
    const int n = dwPerWave >> 8;     // 1 KB per instruction
    #pragma unroll 4
    for (int i = 0; i < n; ++i) {
        async_ld16(base + i * 256 + lane * 4, &pb[wave][(i & 3) << 8], lane);
    }
    asm volatile("s_waitcnt vmcnt(0)" ::: "memory");
    if (lane == 0) sink[blockIdx.x] = pb[wave][wave];
}

extern "C" void kernel_launch(void* const* d_in, const int* in_sizes, int n_in,
                              void* d_out, int out_size, void* d_ws, size_t ws_size,
                              hipStream_t stream) {
    const float* x = (const float*)d_in[0];
    float* out = (float*)d_out;
    hipMemsetAsync(out, 0, (size_t)out_size * sizeof(float), stream);
    logsig_mfma<<<dim3(kB * 2), dim3(256), 0, stream>>>(x, out);

    int dwPerBlock = (int)(((ws_size / 4) / 2048) & ~(size_t)1023);
    if (dwPerBlock >= 1024)
        bw_probe<<<dim3(2048), dim3(256), 0, stream>>>(
            (const uint32_t*)d_ws, (uint32_t*)d_ws, dwPerBlock);
}

// Round 11
// 189.444 us; speedup vs baseline: 1.5577x; 1.5577x over previous
//
#include <hip/hip_runtime.h>
#include <stdint.h>

// LogSig depth-2 via MFMA, line-dense async staging, high occupancy.
// R10 probe facts: global_load_lds fire-hose = 4.33 TB/s effective read
// (cold == L3-warm -> path-bound, not HBM-bound). Kernel floor = 134 MB /
// 4.33 TB/s ~= 31 us. R10 candidate hit 37.6 us at 2 blocks/CU; this round
// doubles occupancy (33.8 KB LDS -> 4 blocks/CU, grid 1024 fills exactly).
//
// Math (verified R4-R10): M = sum_t x[t] (x) x[t+1], K=2047 padded by row
// clamp (symmetric bogus term cancels); A = 0.5*(M - M^T - x0(x)L1 +
// L1(x)x0), L1 = x[2047]-x[0]; fp32 -> truncation hi/lo split,
// M ~= aH*bH + aH*bL + aL*bH, 12 MFMA/panel, absmax ~0.5.
//
// Staging: per wave, panel = 32 rows = 4 chunks x (8 rows x 32 dw), each
// chunk one global_load_lds dwordx4 (1 KB contiguous). Wave-private double
// buffer, chunk skew +8 dw -> all LDS reads 2-way (free, m136). Halo row
// (panel row 32) = chunk 0 of next panel's buffer, complete under vmcnt(3)
// (in-order completion, m135); last panel falls back to 2 clamped dwords.

constexpr int kB   = 512;
constexpr int kL   = 2048;
constexpr int kD   = 32;
constexpr int kOut = 528;
constexpr int kPan = 32;            // rows per K=32 panel
constexpr int kTw  = 256;           // rows per wave
constexpr int kNP  = kTw / kPan;    // 8 panels
constexpr int kCh  = 264;           // dwords per 8-row chunk (256 + 8 skew)
constexpr int kPB  = 4 * kCh;       // panel buffer (4 chunks)

typedef __attribute__((ext_vector_type(8))) short bfrag;
typedef __attribute__((ext_vector_type(4))) float f4acc;
union FragU { uint32_t u[4]; bfrag f; };

#if defined(__has_builtin)
#if __has_builtin(__builtin_amdgcn_global_load_lds)
#define LOGSIG_ASYNC_LDS 1
#endif
#endif

__device__ __forceinline__ void async_ld16(const uint32_t* g, uint32_t* l, int lane) {
#ifdef LOGSIG_ASYNC_LDS
    auto* gp = reinterpret_cast<const __attribute__((address_space(1))) uint32_t*>(
        reinterpret_cast<uintptr_t>(g));
    auto* lp = reinterpret_cast<__attribute__((address_space(3))) uint32_t*>(
        reinterpret_cast<uintptr_t>(l));
    __builtin_amdgcn_global_load_lds(gp, lp, 16, 0, 0);
#else
    *(float4*)(l + lane * 4) = *(const float4*)g;
#endif
}

__global__ __launch_bounds__(256, 4)
void logsig_mfma(const float* __restrict__ x, float* __restrict__ out) {
    __shared__ __align__(16) uint32_t sStage[4][2][kPB];   // 33.8 KB, wave-private
    __shared__ float sx0[kD], sL1[kD];

    const int b     = blockIdx.x >> 1;
    const int chunk = blockIdx.x & 1;
    const int tid   = threadIdx.x;
    const int wave  = tid >> 6;
    const int lane  = tid & 63;
    const int m     = lane & 15;   // MFMA m/n index
    const int q     = lane >> 4;   // quad: k = q*8 + j

    const float* __restrict__ xb = x + (size_t)b * (kL * kD);
    const int t0w = chunk * 1024 + wave * kTw;

    // stage one 32-row panel: 4 x 1KB line-dense, chunk 0 issued FIRST
    // (in-order vmcnt: "p complete + chunk0 of p+1" == oldest 5 of 8).
    auto stage_panel = [&](int p, int buf) {
        uint32_t* dst = &sStage[wave][buf][0];
        const int rbase = t0w + p * kPan;
        #pragma unroll
        for (int c = 0; c < 4; ++c) {
            int r = rbase + c * 8 + (lane >> 3);
            r = r < kL - 1 ? r : kL - 1;                    // tail clamp
            const uint32_t* g = (const uint32_t*)xb + (size_t)r * kD + (lane & 7) * 4;
            async_ld16(g, dst + c * kCh, lane);
        }
    };

    f4acc acc[4];
    #pragma unroll
    for (int t = 0; t < 4; ++t)
        #pragma unroll
        for (int e = 0; e < 4; ++e) acc[t][e] = 0.0f;

    auto make_frags = [&](const uint32_t* e, FragU& AH, FragU& AL,
                          FragU& BH, FragU& BL) {
        uint32_t l[9];
        #pragma unroll
        for (int j = 0; j < 9; ++j) {
            const uint32_t fh = e[j] & 0xffff0000u;
            const float r = __builtin_bit_cast(float, e[j])
                          - __builtin_bit_cast(float, fh);
            l[j] = __builtin_bit_cast(uint32_t, r);
        }
        #pragma unroll
        for (int d = 0; d < 4; ++d) {
            AH.u[d] = __builtin_amdgcn_perm(e[2*d+1], e[2*d],   0x07060302u);
            AL.u[d] = __builtin_amdgcn_perm(l[2*d+1], l[2*d],   0x07060302u);
            BH.u[d] = __builtin_amdgcn_perm(e[2*d+2], e[2*d+1], 0x07060302u);
            BL.u[d] = __builtin_amdgcn_perm(l[2*d+2], l[2*d+1], 0x07060302u);
        }
    };

    stage_panel(0, 0);   // 4 outstanding

    #pragma unroll
    for (int p = 0; p < kNP; ++p) {
        const int cu = p & 1, nb = cu ^ 1;

        // last-panel halo fallback: panel row 32 (= t0w+256, next wave's first
        // row; clamped at the sequence end -> symmetric term cancels)
        uint32_t h0 = 0, h1 = 0;
        if (p == kNP - 1) {
            int hr = t0w + kTw;
            hr = hr < kL - 1 ? hr : kL - 1;
            const uint32_t* g = (const uint32_t*)xb + (size_t)hr * kD;
            h0 = g[m];
            h1 = g[m + 16];
        }

        if (p + 1 < kNP) {
            stage_panel(p + 1, nb);                          // up to 8 outstanding
            asm volatile("s_waitcnt vmcnt(3)" ::: "memory"); // p done + p+1 chunk0
        } else {
            asm volatile("s_waitcnt vmcnt(0)" ::: "memory");
        }

        const uint32_t* sb = &sStage[wave][cu][0];
        uint32_t e0[9], e1[9];
        #pragma unroll
        for (int j = 0; j < 8; ++j) {
            const int a = q * kCh + j * 32 + m;   // bank (8q+m)%32: 2-way, free
            e0[j] = sb[a];
            e1[j] = sb[a + 16];
        }
        if (p == kNP - 1 && q == 3) {
            e0[8] = h0;
            e1[8] = h1;
        } else {
            // q<3: chunk q+1 row 0 (same buffer); q==3: next buffer chunk 0
            const uint32_t* hb = (q < 3) ? sb + (q + 1) * kCh
                                         : &sStage[wave][nb][0];
            e0[8] = hb[m];
            e1[8] = hb[m + 16];
        }

        FragU A0H, A0L, B0H, B0L, A1H, A1L, B1H, B1L;
        make_frags(e0, A0H, A0L, B0H, B0L);
        make_frags(e1, A1H, A1L, B1H, B1L);

        acc[0] = __builtin_amdgcn_mfma_f32_16x16x32_bf16(A0H.f, B0H.f, acc[0], 0, 0, 0);
        acc[0] = __builtin_amdgcn_mfma_f32_16x16x32_bf16(A0H.f, B0L.f, acc[0], 0, 0, 0);
        acc[0] = __builtin_amdgcn_mfma_f32_16x16x32_bf16(A0L.f, B0H.f, acc[0], 0, 0, 0);
        acc[1] = __builtin_amdgcn_mfma_f32_16x16x32_bf16(A0H.f, B1H.f, acc[1], 0, 0, 0);
        acc[1] = __builtin_amdgcn_mfma_f32_16x16x32_bf16(A0H.f, B1L.f, acc[1], 0, 0, 0);
        acc[1] = __builtin_amdgcn_mfma_f32_16x16x32_bf16(A0L.f, B1H.f, acc[1], 0, 0, 0);
        acc[2] = __builtin_amdgcn_mfma_f32_16x16x32_bf16(A1H.f, B0H.f, acc[2], 0, 0, 0);
        acc[2] = __builtin_amdgcn_mfma_f32_16x16x32_bf16(A1H.f, B0L.f, acc[2], 0, 0, 0);
        acc[2] = __builtin_amdgcn_mfma_f32_16x16x32_bf16(A1L.f, B0H.f, acc[2], 0, 0, 0);
        acc[3] = __builtin_amdgcn_mfma_f32_16x16x32_bf16(A1H.f, B1H.f, acc[3], 0, 0, 0);
        acc[3] = __builtin_amdgcn_mfma_f32_16x16x32_bf16(A1H.f, B1L.f, acc[3], 0, 0, 0);
        acc[3] = __builtin_amdgcn_mfma_f32_16x16x32_bf16(A1L.f, B1H.f, acc[3], 0, 0, 0);
    }

    // ---- epilogue: overlay per-wave M on dead stage buffers, reduce, emit ----
    float* sWw = (float*)&sStage[wave][0][0];
    #pragma unroll
    for (int t = 0; t < 4; ++t) {
        const int tr = t >> 1, tc = t & 1;
        #pragma unroll
        for (int e = 0; e < 4; ++e) {
            const int row = 16 * tr + q * 4 + e;   // C/D layout (m89-verified)
            const int col = 16 * tc + m;
            sWw[row * kD + col] = acc[t][e];
        }
    }
    if (tid < kD) {
        const float x0v = xb[tid];
        const float xev = xb[(size_t)(kL - 1) * kD + tid];
        sx0[tid] = x0v;
        sL1[tid] = xev - x0v;
    }
    __syncthreads();

    float* sW0 = (float*)&sStage[0][0][0];
    for (int c = tid; c < kD * kD; c += 256)
        sW0[c] += ((float*)&sStage[1][0][0])[c]
                + ((float*)&sStage[2][0][0])[c]
                + ((float*)&sStage[3][0][0])[c];
    __syncthreads();

    float* ob = out + (size_t)b * kOut;
    for (int o = tid; o < kOut; o += 256) {
        if (o < 32) {
            if (chunk == 0) ob[o] = sL1[o];
        } else {
            int p = o - 32, i = 0;
            while (p >= 31 - i) { p -= 31 - i; ++i; }
            const int j = i + 1 + p;
            float v = 0.5f * (sW0[i * kD + j] - sW0[j * kD + i]);
            if (chunk == 0)
                v += 0.5f * (sx0[j] * sL1[i] - sx0[i] * sL1[j]);
            atomicAdd(ob + o, v);
        }
    }
}

extern "C" void kernel_launch(void* const* d_in, const int* in_sizes, int n_in,
                              void* d_out, int out_size, void* d_ws, size_t ws_size,
                              hipStream_t stream) {
    const float* x = (const float*)d_in[0];
    float* out = (float*)d_out;
    hipMemsetAsync(out, 0, (size_t)out_size * sizeof(float), stream);
    logsig_mfma<<<dim3(kB * 2), dim3(256), 0, stream>>>(x, out);
}